// Round 9
// baseline (1991.159 us; speedup 1.0000x reference)
//
#include <hip/hip_runtime.h>
#include <hip/hip_bf16.h>

#define NN 4096    // nodes == feature dim
#define NE 32768   // edges
#define NEMB 8

typedef __bf16 bf16x8 __attribute__((ext_vector_type(8)));
typedef float  f32x4  __attribute__((ext_vector_type(4)));

__device__ __forceinline__ unsigned short f2bf(float f) {
  union { float f; unsigned int u; } v; v.f = f;
  return (unsigned short)((v.u + 0x7FFFu + ((v.u >> 16) & 1u)) >> 16);
}

// ---------------- f32 -> bf16 bulk convert ----------------
__global__ void k_f2bf(const float* __restrict__ in, unsigned short* __restrict__ out, long n8) {
  long i = (long)blockIdx.x * blockDim.x + threadIdx.x;
  long stride = (long)gridDim.x * blockDim.x;
  for (long j = i; j < n8; j += stride) {
    const float* p = in + j * 8;
    float4 a = *(const float4*)p;
    float4 b = *(const float4*)(p + 4);
    union { unsigned short u[8]; uint4 v; } o;
    o.u[0] = f2bf(a.x); o.u[1] = f2bf(a.y); o.u[2] = f2bf(a.z); o.u[3] = f2bf(a.w);
    o.u[4] = f2bf(b.x); o.u[5] = f2bf(b.y); o.u[6] = f2bf(b.z); o.u[7] = f2bf(b.w);
    *(uint4*)(out + j * 8) = o.v;
  }
}

// ---------------- graph prep ----------------
__global__ void k_deg_init(float* deg) { deg[blockIdx.x * 256 + threadIdx.x] = 1.0f; }

__global__ void k_edge_accum(const int* __restrict__ ei, const float* __restrict__ ew,
                             float* deg, int* cnt) {
  int e = blockIdx.x * 256 + threadIdx.x;
  if (e >= NE) return;
  int c = ei[NE + e];
  atomicAdd(&deg[c], ew[e]);
  atomicAdd(&cnt[c], 1);
}

__global__ void k_dis(const float* __restrict__ deg, float* __restrict__ dis) {
  int i = blockIdx.x * 256 + threadIdx.x;
  float d = deg[i];
  dis[i] = d > 0.f ? rsqrtf(d) : 0.f;
}

__global__ void k_scan(const int* __restrict__ cnt, int* __restrict__ starts) {
  __shared__ int sh[1024];
  int tid = threadIdx.x;
  int base = tid * 4;
  int v[4]; int sum = 0;
  for (int i = 0; i < 4; i++) { v[i] = cnt[base + i]; sum += v[i]; }
  sh[tid] = sum;
  __syncthreads();
  for (int offd = 1; offd < 1024; offd <<= 1) {
    int t = (tid >= offd) ? sh[tid - offd] : 0;
    __syncthreads();
    sh[tid] += t;
    __syncthreads();
  }
  int run = sh[tid] - sum;
  for (int i = 0; i < 4; i++) { starts[base + i] = run; run += v[i]; }
}

__global__ void k_fill(const int* __restrict__ ei, const int* __restrict__ starts,
                       int* cursor, int* csr_e) {
  int e = blockIdx.x * 256 + threadIdx.x;
  if (e >= NE) return;
  int c = ei[NE + e];
  int pos = atomicAdd(&cursor[c], 1);
  csr_e[starts[c] + pos] = e;
}

__global__ void k_sortnorm(const int* __restrict__ ei, const float* __restrict__ ew,
                           const int* __restrict__ starts, const int* __restrict__ cnt,
                           const float* __restrict__ dis,
                           int* csr_e, int* __restrict__ csr_row, float* __restrict__ csr_nrm) {
  int n = blockIdx.x * 256 + threadIdx.x;
  if (n >= NN) return;
  int s = starts[n], c = cnt[n];
  for (int i = 1; i < c; i++) {
    int key = csr_e[s + i]; int j = i - 1;
    while (j >= 0 && csr_e[s + j] > key) { csr_e[s + j + 1] = csr_e[s + j]; j--; }
    csr_e[s + j + 1] = key;
  }
  float dn = dis[n];
  for (int i = 0; i < c; i++) {
    int e = csr_e[s + i];
    int r = ei[e];
    csr_row[s + i] = r;
    csr_nrm[s + i] = dis[r] * ew[e] * dn;
  }
}

// ---------------- aggregate + tanh -> H1 (bf16) ----------------
__global__ __launch_bounds__(256) void k_agg(
    const float* __restrict__ h, const float* __restrict__ dis,
    const int* __restrict__ starts, const int* __restrict__ cnt,
    const int* __restrict__ csr_row, const float* __restrict__ csr_nrm,
    const float* __restrict__ gcn_b, unsigned short* __restrict__ H1b) {
  int n = blockIdx.x;
  int tid = threadIdx.x;
  float dn = dis[n];
  float sw = dn * dn;
  float acc[16];
  const float* hn = h + (size_t)n * NN;
  #pragma unroll
  for (int i = 0; i < 16; i++) { int f = tid + i * 256; acc[i] = sw * hn[f] + gcn_b[f]; }
  int s = starts[n], c = cnt[n];
  __shared__ int   s_row[64];
  __shared__ float s_nrm[64];
  for (int base = 0; base < c; base += 64) {
    int m = min(64, c - base);
    __syncthreads();
    if (tid < m) { s_row[tid] = csr_row[s + base + tid]; s_nrm[tid] = csr_nrm[s + base + tid]; }
    __syncthreads();
    for (int j = 0; j < m; j++) {
      const float* hr = h + (size_t)s_row[j] * NN;
      float wgt = s_nrm[j];
      #pragma unroll
      for (int i = 0; i < 16; i++) acc[i] += wgt * hr[tid + i * 256];
    }
  }
  #pragma unroll
  for (int i = 0; i < 16; i++)
    H1b[(size_t)n * NN + tid + i * 256] = f2bf(tanhf(acc[i]));
}

// ---- 4-wave (1/SIMD) 256x128 GEMM, reg-pipelined reads, ring-4 LDS, stage-ahead ----
__device__ __forceinline__ void gload16(const void* g, void* l) {
  __builtin_amdgcn_global_load_lds(
      (const __attribute__((address_space(1))) unsigned int*)g,
      (__attribute__((address_space(3))) unsigned int*)l, 16, 0, 0);
}

#define BARX() do { __builtin_amdgcn_sched_barrier(0); __builtin_amdgcn_s_barrier(); __builtin_amdgcn_sched_barrier(0); } while (0)
#define LGKM(n) do { asm volatile("s_waitcnt lgkmcnt(" #n ")" ::: "memory"); __builtin_amdgcn_sched_barrier(0); } while (0)
#define VMC(n) do { asm volatile("s_waitcnt vmcnt(" #n ")" ::: "memory"); } while (0)

// LDS ring: 4 slots x (A frags 0..15 | B frags 16..23) x 1KB.  96 KiB total.
// Half h (K cols h*32..h*32+31) lives in slot h&3. Producer/consumer XOR layout
// identical to r4 (verified): lane l=4q+j stages M[frag*16+q][chunk j^((q>>1)&3)];
// consumer lane (r,c) reads slot 4r + (c ^ ((r>>1)&3)) -> 0 bank conflicts,
// 64-B coalesced global segments.
//
// SCHEDULE (per 8-phase iteration = 2 K-tiles = halves 4i..4i+3):
//  - reads for phase p+1 issued at p into alternating reg sets (avA/avB, bvA/bvB);
//    LGKM(4|8) at p retires exactly phase p's reads (landed under p's own window).
//  - odd phases stage the half 6 phases ahead (A 4 + B 2 gloads/wave):
//    ph1->h+3(slot3), ph3->h+4(slot0), ph5->h+5(slot1), ph7->h+6(slot2).
//  - VMC(12) at every odd-phase end keeps the last 2 stages (12 loads) in flight,
//    retiring the 3-ago stage exactly one barrier before its first read (~4-phase
//    HBM cover). Tail: VMC(6)@ph3, VMC(0)@ph5 of the last iteration.

#define STAGE_H(slot, h) do { \
    size_t off_ = (size_t)(h) * 32; \
    gload16(gA0 + off_, &LDS[slot][c0a + 0][0]); \
    gload16(gA1 + off_, &LDS[slot][c0a + 1][0]); \
    gload16(gA2 + off_, &LDS[slot][c0a + 2][0]); \
    gload16(gA3 + off_, &LDS[slot][c0a + 3][0]); \
    gload16(gB0 + off_, &LDS[slot][c0b + 0][0]); \
    gload16(gB1 + off_, &LDS[slot][c0b + 1][0]); \
  } while (0)

#define LDA4(dst, slot, q) do { \
    const unsigned short* b_ = &LDS[slot][wr * 8 + (q) * 4][0] + aoff; \
    dst[0] = *(const bf16x8*)(b_); \
    dst[1] = *(const bf16x8*)(b_ + 512); \
    dst[2] = *(const bf16x8*)(b_ + 1024); \
    dst[3] = *(const bf16x8*)(b_ + 1536); \
  } while (0)

#define LDB4(dst, slot) do { \
    const unsigned short* b_ = &LDS[slot][16 + wc * 4][0] + aoff; \
    dst[0] = *(const bf16x8*)(b_); \
    dst[1] = *(const bf16x8*)(b_ + 512); \
    dst[2] = *(const bf16x8*)(b_ + 1024); \
    dst[3] = *(const bf16x8*)(b_ + 1536); \
  } while (0)

#define MMA16(q, av, bv) do { \
    __builtin_amdgcn_s_setprio(1); \
    _Pragma("unroll") \
    for (int mf_ = 0; mf_ < 4; mf_++) \
      _Pragma("unroll") \
      for (int nf_ = 0; nf_ < 4; nf_++) \
        acc[(q) * 4 + mf_][nf_] = __builtin_amdgcn_mfma_f32_16x16x32_bf16(av[mf_], bv[nf_], acc[(q) * 4 + mf_][nf_], 0, 0, 0); \
    __builtin_amdgcn_s_setprio(0); \
  } while (0)

template<bool FUSED>
__global__ __launch_bounds__(256, 1) void gemm4(
    const unsigned short* __restrict__ A,  // [M][K] bf16
    const unsigned short* __restrict__ B,  // [N][K] bf16
    int N, int K,
    float* __restrict__ outF,
    const float* __restrict__ colBias,
    const float* __restrict__ rowW,
    float* __restrict__ P) {
  __shared__ unsigned short LDS[4][24][512];  // 96 KiB

  const int nwg = gridDim.x, n8 = nwg >> 3;
  const int bid = blockIdx.x;
  const int swz = (bid & 7) * n8 + (bid >> 3);   // XCD-aware, bijective (nwg % 8 == 0)
  // locality: 32 consecutive swz = {16 rb} x {2 cb halves} of one 256-col stripe
  const int rb = swz & 15;
  const int cb = (swz >> 5) * 2 + ((swz >> 4) & 1);
  const int row0 = rb * 256, col0 = cb * 128;

  const int tid = threadIdx.x;
  const int w = tid >> 6, l = tid & 63;
  const int wr = w >> 1, wc = w & 1;             // 2M x 2N wave grid, 128x64/wave
  const int l15 = l & 15, kl = l >> 4;

  // producer gather (lane l = 4q+j)
  const int c0a = w * 4;                          // A frags staged by this wave
  const int c0b = 16 + w * 2;                     // B frags staged by this wave
  const int pq = l >> 2;
  const int pc = (l & 3) ^ ((l >> 3) & 3);
  const unsigned short* gA0 = A + (size_t)(row0 + (w * 4) * 16 + pq) * K + pc * 8;
  const unsigned short* gA1 = gA0 + (size_t)16 * K;
  const unsigned short* gA2 = gA0 + (size_t)32 * K;
  const unsigned short* gA3 = gA0 + (size_t)48 * K;
  const unsigned short* gB0 = B + (size_t)(col0 + (w * 2) * 16 + pq) * K + pc * 8;
  const unsigned short* gB1 = gB0 + (size_t)16 * K;

  // consumer read offset within a frag block (shorts)
  const int aoff = l15 * 32 + ((kl ^ ((l >> 1) & 3)) << 3);

  f32x4 acc[8][4];
  #pragma unroll
  for (int m = 0; m < 8; m++)
    #pragma unroll
    for (int n = 0; n < 4; n++)
      acc[m][n] = f32x4{0.f, 0.f, 0.f, 0.f};

  bf16x8 avA[4], avB[4], bvA[4], bvB[4];

  // prologue: stage halves 0,1,2; retire h0; preload ph1 fragments
  STAGE_H(0, 0); STAGE_H(1, 1); STAGE_H(2, 2);
  VMC(12);
  BARX();
  LDB4(bvA, 0); LDA4(avA, 0, 0);

  const int NIT = K >> 7;   // 4 halves (2 K-tiles) per iteration
  for (int i = 0; i < NIT; i++) {
    const bool mid = (i < NIT - 1);
    const int h0 = 4 * i;
    // ph1 [q0, half h0, slot0] | early: av q1 | stage h0+3 -> slot3
    LDA4(avB, 0, 1);
    STAGE_H(3, h0 + 3);
    LGKM(4); MMA16(0, avA, bvA); VMC(12); BARX();
    // ph2 [q1, h0, slot0] | early: bv+av q0 of h0+1 (slot1)
    LDB4(bvB, 1); LDA4(avA, 1, 0);
    LGKM(8); MMA16(1, avB, bvA); BARX();
    // ph3 [q0, h0+1, slot1] | early: av q1 | stage h0+4 -> slot0
    LDA4(avB, 1, 1);
    if (mid) STAGE_H(0, h0 + 4);
    LGKM(4); MMA16(0, avA, bvB);
    if (mid) VMC(12); else VMC(6);
    BARX();
    // ph4 [q1, h0+1, slot1] | early: bv+av q0 of h0+2 (slot2)
    LDB4(bvA, 2); LDA4(avA, 2, 0);
    LGKM(8); MMA16(1, avB, bvB); BARX();
    // ph5 [q0, h0+2, slot2] | early: av q1 | stage h0+5 -> slot1
    LDA4(avB, 2, 1);
    if (mid) STAGE_H(1, h0 + 5);
    LGKM(4); MMA16(0, avA, bvA);
    if (mid) VMC(12); else VMC(0);
    BARX();
    // ph6 [q1, h0+2, slot2] | early: bv+av q0 of h0+3 (slot3)
    LDB4(bvB, 3); LDA4(avA, 3, 0);
    LGKM(8); MMA16(1, avB, bvA); BARX();
    // ph7 [q0, h0+3, slot3] | early: av q1 | stage h0+6 -> slot2
    LDA4(avB, 3, 1);
    if (mid) STAGE_H(2, h0 + 6);
    LGKM(4); MMA16(0, avA, bvB);
    if (mid) VMC(12);
    BARX();
    // ph8 [q1, h0+3, slot3] | early: bv+av q0 of h0+4 (slot0)
    if (mid) {
      LDB4(bvA, 0); LDA4(avA, 0, 0);
      LGKM(8); MMA16(1, avB, bvB); BARX();
    } else {
      LGKM(0); MMA16(1, avB, bvB); BARX();
    }
  }

  if (!FUSED) {
    #pragma unroll
    for (int mf = 0; mf < 8; mf++)
      #pragma unroll
      for (int nf = 0; nf < 4; nf++) {
        int row = row0 + wr * 128 + mf * 16 + kl * 4;
        int col = col0 + wc * 64 + nf * 16 + l15;
        float* o = outF + (size_t)row * N + col;
        #pragma unroll
        for (int r = 0; r < 4; r++) o[(size_t)r * N] = acc[mf][nf][r];
      }
  } else {
    #pragma unroll
    for (int nf = 0; nf < 4; nf++) {
      int col = col0 + wc * 64 + nf * 16 + l15;
      float bias = colBias[col];
      float s = 0.f;
      #pragma unroll
      for (int mf = 0; mf < 8; mf++) {
        int rbase = row0 + wr * 128 + mf * 16 + kl * 4;
        #pragma unroll
        for (int r = 0; r < 4; r++)
          s += rowW[rbase + r] * tanhf(acc[mf][nf][r] + bias);
      }
      s += __shfl_xor(s, 16, 64);
      s += __shfl_xor(s, 32, 64);
      if (l < 16) P[(size_t)(rb * 2 + wr) * N + col] = s;
    }
  }
}

// ---------------- final deterministic reduction ----------------
__global__ void k_final(const float* __restrict__ P, const float* __restrict__ emb,
                        const float* __restrict__ wf, const float* __restrict__ wfb,
                        float* __restrict__ out) {
  int e = blockIdx.x * 256 + threadIdx.x;
  float s = 0.f;
  for (int r = 0; r < 32; r++) s += P[(size_t)r * NE + e];
  float c = wfb[0];
  #pragma unroll
  for (int k = 0; k < NEMB; k++) c += emb[e * NEMB + k] * wf[NN + k];
  out[e] = s + c;
}

extern "C" void kernel_launch(void* const* d_in, const int* in_sizes, int n_in,
                              void* d_out, int out_size, void* d_ws, size_t ws_size,
                              hipStream_t stream) {
  const float* x    = (const float*)d_in[0];
  const int*   ei   = (const int*)d_in[1];
  const float* ew   = (const float*)d_in[2];
  const float* gcnw = (const float*)d_in[3];
  const float* gcnb = (const float*)d_in[4];
  const float* wqw  = (const float*)d_in[5];
  const float* wqb  = (const float*)d_in[6];
  const float* emb  = (const float*)d_in[7];
  const float* wfw  = (const float*)d_in[8];
  const float* wfb  = (const float*)d_in[9];
  float* out = (float*)d_out;

  char* ws = (char*)d_ws;
  size_t off = 0;
  auto alloc = [&](size_t b) { char* p = ws + off; off += (b + 255) & ~(size_t)255; return p; };

  unsigned short* wq16  = (unsigned short*)alloc((size_t)NE * NN * 2); // 256MB
  float*          h     = (float*)alloc((size_t)NN * NN * 4);          // 64MB
  unsigned short* x16   = (unsigned short*)alloc((size_t)NN * NN * 2); // 32MB
  unsigned short* w16   = (unsigned short*)alloc((size_t)NN * NN * 2); // 32MB
  unsigned short* h1b   = (unsigned short*)alloc((size_t)NN * NN * 2); // 32MB
  float* deg    = (float*)alloc(NN * 4);
  float* dis    = (float*)alloc(NN * 4);
  int*   cnt    = (int*)alloc(NN * 4);
  int*   cursor = (int*)alloc(NN * 4);
  int*   starts = (int*)alloc(NN * 4);
  int*   csr_e  = (int*)alloc(NE * 4);
  int*   csr_row= (int*)alloc(NE * 4);
  float* csr_nrm= (float*)alloc(NE * 4);
  float* P      = (float*)alloc((size_t)32 * NE * 4);                  // 4MB

  hipMemsetAsync(cnt, 0, NN * 4 * 2, stream);  // zero cnt + cursor

  k_deg_init<<<NN / 256, 256, 0, stream>>>(deg);
  k_edge_accum<<<NE / 256, 256, 0, stream>>>(ei, ew, deg, cnt);
  k_dis<<<NN / 256, 256, 0, stream>>>(deg, dis);
  k_scan<<<1, 1024, 0, stream>>>(cnt, starts);
  k_fill<<<NE / 256, 256, 0, stream>>>(ei, starts, cursor, csr_e);
  k_sortnorm<<<NN / 256, 256, 0, stream>>>(ei, ew, starts, cnt, dis, csr_e, csr_row, csr_nrm);

  k_f2bf<<<1024, 256, 0, stream>>>(x, x16, (long)NN * NN / 8);
  k_f2bf<<<1024, 256, 0, stream>>>(gcnw, w16, (long)NN * NN / 8);
  k_f2bf<<<2048, 256, 0, stream>>>(wqw, wq16, (long)NE * NN / 8);

  // h = x @ gcn_w.T   (M=N=K=4096): 16 rb x 32 cb blocks of 256x128
  gemm4<false><<<16 * 32, 256, 0, stream>>>(x16, w16, NN, NN, h, nullptr, nullptr, nullptr);

  // aggregate + tanh -> H1 (bf16)
  k_agg<<<NN, 256, 0, stream>>>(h, dis, starts, cnt, csr_row, csr_nrm, gcnb, h1b);

  // fused: P[rb*2+wr][e] = sum_rows wf[row] * tanh(H1 @ wq_w.T + wq_b)
  gemm4<true><<<16 * 256, 256, 0, stream>>>(h1b, wq16, NE, NN, nullptr, wqb, wfw, P);

  k_final<<<NE / 256, 256, 0, stream>>>(P, emb, wfw, wfb, out);
}

// Round 10
// 1363.826 us; speedup vs baseline: 1.4600x; 1.4600x over previous
//
#include <hip/hip_runtime.h>
#include <hip/hip_bf16.h>

#define NN 4096    // nodes == feature dim
#define NE 32768   // edges
#define NEMB 8

typedef __bf16 bf16x8 __attribute__((ext_vector_type(8)));
typedef float  f32x4  __attribute__((ext_vector_type(4)));

__device__ __forceinline__ unsigned short f2bf(float f) {
  union { float f; unsigned int u; } v; v.f = f;
  return (unsigned short)((v.u + 0x7FFFu + ((v.u >> 16) & 1u)) >> 16);
}
__device__ __forceinline__ float b2f(unsigned short u) {
  union { unsigned int u; float f; } v; v.u = ((unsigned int)u) << 16;
  return v.f;
}

// ---------------- f32 -> bf16 bulk convert ----------------
__global__ void k_f2bf(const float* __restrict__ in, unsigned short* __restrict__ out, long n8) {
  long i = (long)blockIdx.x * blockDim.x + threadIdx.x;
  long stride = (long)gridDim.x * blockDim.x;
  for (long j = i; j < n8; j += stride) {
    const float* p = in + j * 8;
    float4 a = *(const float4*)p;
    float4 b = *(const float4*)(p + 4);
    union { unsigned short u[8]; uint4 v; } o;
    o.u[0] = f2bf(a.x); o.u[1] = f2bf(a.y); o.u[2] = f2bf(a.z); o.u[3] = f2bf(a.w);
    o.u[4] = f2bf(b.x); o.u[5] = f2bf(b.y); o.u[6] = f2bf(b.z); o.u[7] = f2bf(b.w);
    *(uint4*)(out + j * 8) = o.v;
  }
}

// ---------------- graph prep ----------------
__global__ void k_deg_init(float* deg) { deg[blockIdx.x * 256 + threadIdx.x] = 1.0f; }

__global__ void k_edge_accum(const int* __restrict__ ei, const float* __restrict__ ew,
                             float* deg, int* cnt) {
  int e = blockIdx.x * 256 + threadIdx.x;
  if (e >= NE) return;
  int c = ei[NE + e];
  atomicAdd(&deg[c], ew[e]);
  atomicAdd(&cnt[c], 1);
}

__global__ void k_dis(const float* __restrict__ deg, float* __restrict__ dis) {
  int i = blockIdx.x * 256 + threadIdx.x;
  float d = deg[i];
  dis[i] = d > 0.f ? rsqrtf(d) : 0.f;
}

__global__ void k_scan(const int* __restrict__ cnt, int* __restrict__ starts) {
  __shared__ int sh[1024];
  int tid = threadIdx.x;
  int base = tid * 4;
  int v[4]; int sum = 0;
  for (int i = 0; i < 4; i++) { v[i] = cnt[base + i]; sum += v[i]; }
  sh[tid] = sum;
  __syncthreads();
  for (int offd = 1; offd < 1024; offd <<= 1) {
    int t = (tid >= offd) ? sh[tid - offd] : 0;
    __syncthreads();
    sh[tid] += t;
    __syncthreads();
  }
  int run = sh[tid] - sum;
  for (int i = 0; i < 4; i++) { starts[base + i] = run; run += v[i]; }
}

__global__ void k_fill(const int* __restrict__ ei, const int* __restrict__ starts,
                       int* cursor, int* csr_e) {
  int e = blockIdx.x * 256 + threadIdx.x;
  if (e >= NE) return;
  int c = ei[NE + e];
  int pos = atomicAdd(&cursor[c], 1);
  csr_e[starts[c] + pos] = e;
}

__global__ void k_sortnorm(const int* __restrict__ ei, const float* __restrict__ ew,
                           const int* __restrict__ starts, const int* __restrict__ cnt,
                           const float* __restrict__ dis,
                           int* csr_e, int* __restrict__ csr_row, float* __restrict__ csr_nrm) {
  int n = blockIdx.x * 256 + threadIdx.x;
  if (n >= NN) return;
  int s = starts[n], c = cnt[n];
  for (int i = 1; i < c; i++) {
    int key = csr_e[s + i]; int j = i - 1;
    while (j >= 0 && csr_e[s + j] > key) { csr_e[s + j + 1] = csr_e[s + j]; j--; }
    csr_e[s + j + 1] = key;
  }
  float dn = dis[n];
  for (int i = 0; i < c; i++) {
    int e = csr_e[s + i];
    int r = ei[e];
    csr_row[s + i] = r;
    csr_nrm[s + i] = dis[r] * ew[e] * dn;
  }
}

// ---------------- aggregate + tanh -> H1 (bf16); h is bf16 now ----------------
__global__ __launch_bounds__(256) void k_agg(
    const unsigned short* __restrict__ h, const float* __restrict__ dis,
    const int* __restrict__ starts, const int* __restrict__ cnt,
    const int* __restrict__ csr_row, const float* __restrict__ csr_nrm,
    const float* __restrict__ gcn_b, unsigned short* __restrict__ H1b) {
  int n = blockIdx.x;
  int tid = threadIdx.x;
  float dn = dis[n];
  float sw = dn * dn;
  float acc[16];
  const unsigned short* hn = h + (size_t)n * NN;
  #pragma unroll
  for (int i = 0; i < 16; i++) { int f = tid + i * 256; acc[i] = sw * b2f(hn[f]) + gcn_b[f]; }
  int s = starts[n], c = cnt[n];
  __shared__ int   s_row[64];
  __shared__ float s_nrm[64];
  for (int base = 0; base < c; base += 64) {
    int m = min(64, c - base);
    __syncthreads();
    if (tid < m) { s_row[tid] = csr_row[s + base + tid]; s_nrm[tid] = csr_nrm[s + base + tid]; }
    __syncthreads();
    for (int j = 0; j < m; j++) {
      const unsigned short* hr = h + (size_t)s_row[j] * NN;
      float wgt = s_nrm[j];
      #pragma unroll
      for (int i = 0; i < 16; i++) acc[i] += wgt * b2f(hr[tid + i * 256]);
    }
  }
  #pragma unroll
  for (int i = 0; i < 16; i++)
    H1b[(size_t)n * NN + tid + i * 256] = f2bf(tanhf(acc[i]));
}

// ---- 8-phase 256x256 GEMM: lag-1 MMA, per-frag A-read recycling, 1 barrier/phase ----
__device__ __forceinline__ void gload16(const void* g, void* l) {
  __builtin_amdgcn_global_load_lds(
      (const __attribute__((address_space(1))) unsigned int*)g,
      (__attribute__((address_space(3))) unsigned int*)l, 16, 0, 0);
}

#define BARX() do { __builtin_amdgcn_sched_barrier(0); __builtin_amdgcn_s_barrier(); __builtin_amdgcn_sched_barrier(0); } while (0)
#define VMC(n) do { asm volatile("s_waitcnt vmcnt(" #n ")" ::: "memory"); } while (0)

// LDS: [buf][A/B][kk][frag 0..15][64 slots x 8 shorts] — identical to r8 (0 conflicts,
// coalesced 64-B producer segments). Reads/stages/VMC sit in their exact r8 slots,
// so the LDS validity + vmcnt ledger is r8's (empirically validated).
//
// NEW SCHEDULE (lag-1): slot s executes slot s-1's 16-MFMA cluster, interleaved:
// after the 4 MFMAs consuming av[mf] issue, av[mf] is dead -> ds_read slot-s's A
// fragment into it (register recycling, +0 VGPR). B reads go at cluster end (old
// bv live through all 4 groups). Reads issued at s retire during {phase tail +
// barrier + next cluster's early groups} -> LDS overlaps the MFMA window instead
// of serializing before it. First slot's MMA guarded (if(i)); trailing MMA after
// the loop completes slot ph8 of the last iteration.

#define STAGE(buf, mat, kk, tk) do { \
    size_t off_ = (size_t)(tk) * 64 + (kk) * 32; \
    gload16((mat ? gB0 : gA0) + off_, &LDS[buf][mat][kk][c0][0]); \
    gload16((mat ? gB1 : gA1) + off_, &LDS[buf][mat][kk][c0 + 1][0]); \
  } while (0)

#define LDA4(dst, buf, kk, q) do { \
    const unsigned short* b_ = &LDS[buf][0][kk][wr * 8 + (q) * 4][0] + aoff; \
    dst[0] = *(const bf16x8*)(b_); \
    dst[1] = *(const bf16x8*)(b_ + 512); \
    dst[2] = *(const bf16x8*)(b_ + 1024); \
    dst[3] = *(const bf16x8*)(b_ + 1536); \
  } while (0)

#define LDB4(dst, buf, kk) do { \
    const unsigned short* b_ = &LDS[buf][1][kk][wc * 4][0] + aoff; \
    dst[0] = *(const bf16x8*)(b_); \
    dst[1] = *(const bf16x8*)(b_ + 512); \
    dst[2] = *(const bf16x8*)(b_ + 1024); \
    dst[3] = *(const bf16x8*)(b_ + 1536); \
  } while (0)

// MMA of q-cluster (old av x old bv) with per-group refill of av from [bufA][kkA][qA]
#define MMA_RDA(q, bufA, kkA, qA) do { \
    __builtin_amdgcn_s_setprio(1); \
    _Pragma("unroll") \
    for (int mf_ = 0; mf_ < 4; mf_++) { \
      _Pragma("unroll") \
      for (int nf_ = 0; nf_ < 4; nf_++) \
        acc[(q) * 4 + mf_][nf_] = __builtin_amdgcn_mfma_f32_16x16x32_bf16(av[mf_], bv[nf_], acc[(q) * 4 + mf_][nf_], 0, 0, 0); \
      const unsigned short* a_ = &LDS[bufA][0][kkA][wr * 8 + (qA) * 4 + mf_][0] + aoff; \
      av[mf_] = *(const bf16x8*)(a_); \
    } \
    __builtin_amdgcn_s_setprio(0); \
  } while (0)

#define MMA16(q) do { \
    __builtin_amdgcn_s_setprio(1); \
    _Pragma("unroll") \
    for (int mf_ = 0; mf_ < 4; mf_++) \
      _Pragma("unroll") \
      for (int nf_ = 0; nf_ < 4; nf_++) \
        acc[(q) * 4 + mf_][nf_] = __builtin_amdgcn_mfma_f32_16x16x32_bf16(av[mf_], bv[nf_], acc[(q) * 4 + mf_][nf_], 0, 0, 0); \
    __builtin_amdgcn_s_setprio(0); \
  } while (0)

template<bool FUSED>
__global__ __launch_bounds__(512, 2) void gemm8(
    const unsigned short* __restrict__ A,  // [M][K] bf16
    const unsigned short* __restrict__ B,  // [N][K] bf16
    int N, int K, int nRb,
    void* __restrict__ outP,               // bf16 [M][N] when !FUSED
    const float* __restrict__ colBias,
    const float* __restrict__ rowW,
    float* __restrict__ P) {
  __shared__ unsigned short LDS[2][2][2][16][512];  // 128 KiB

  const int nwg = gridDim.x, n8 = nwg >> 3;
  const int bid = blockIdx.x;
  const int swz = (bid & 7) * n8 + (bid >> 3);   // XCD-aware, bijective (nwg % 8 == 0)
  const int rb = swz % nRb, cb = swz / nRb;
  const int row0 = rb * 256, col0 = cb * 256;

  const int tid = threadIdx.x;
  const int w = tid >> 6, l = tid & 63;
  const int wr = w >> 2, wc = w & 3;             // 2M x 4N wave grid
  const int l15 = l & 15, kl = l >> 4;

  // producer gather: wave w owns frags c0, c0+1; lane l = 4q+j
  const int c0 = w * 2;
  const int pq = l >> 2;                          // row within 16-row frag
  const int pc = (l & 3) ^ ((l >> 3) & 3);        // XOR-permuted k-chunk (16 B units)
  const unsigned short* gA0 = A + (size_t)(row0 + c0 * 16 + pq) * K + pc * 8;
  const unsigned short* gA1 = gA0 + (size_t)16 * K;
  const unsigned short* gB0 = B + (size_t)(col0 + c0 * 16 + pq) * K + pc * 8;
  const unsigned short* gB1 = gB0 + (size_t)16 * K;

  // consumer read offset within a frag block (shorts): slot 4r + (c ^ ((r>>1)&3))
  const int aoff = l15 * 32 + ((kl ^ ((l >> 1) & 3)) << 3);

  f32x4 acc[8][4];
  #pragma unroll
  for (int m = 0; m < 8; m++)
    #pragma unroll
    for (int n = 0; n < 4; n++)
      acc[m][n] = f32x4{0.f, 0.f, 0.f, 0.f};

  bf16x8 av[4], bv[4];

  // prologue: tile0 fully + tile1 kk0; retire tile0; publish
  STAGE(0, 0, 0, 0); STAGE(0, 1, 0, 0); STAGE(0, 0, 1, 0); STAGE(0, 1, 1, 0);
  STAGE(1, 0, 0, 1); STAGE(1, 1, 0, 1);
  VMC(4);
  BARX();

  const int NIT = K >> 7;   // 2 K-tiles (BK=64) per iteration
  for (int i = 0; i < NIT; i++) {
    const int ta = 2 * i, tb = 2 * i + 1;
    const bool mid = (i < NIT - 1);
    // s1: MMA(prev s8 = q1) + refill av(buf0,kk0,q0) | B(buf0,kk0) | stage A-kk1(tb)
    if (i) {
      MMA_RDA(1, 0, 0, 0);
      LDB4(bv, 0, 0);
    } else {
      LDA4(av, 0, 0, 0);
      LDB4(bv, 0, 0);
    }
    STAGE(1, 0, 1, tb);
    BARX();
    // s2: MMA(s1 = q0) + refill av(buf0,kk0,q1) | stage B-kk1(tb) | VMC(8)
    MMA_RDA(0, 0, 0, 1);
    STAGE(1, 1, 1, tb);
    VMC(8);
    BARX();
    // s3: MMA(s2 = q1) + refill av(buf0,kk1,q0) | B(buf0,kk1) | stage A-kk0(ta+2)
    MMA_RDA(1, 0, 1, 0);
    LDB4(bv, 0, 1);
    if (mid) STAGE(0, 0, 0, ta + 2);
    BARX();
    // s4: MMA(s3 = q0) + refill av(buf0,kk1,q1) | stage B-kk0(ta+2) | VMC(8|4)
    MMA_RDA(0, 0, 1, 1);
    if (mid) STAGE(0, 1, 0, ta + 2);
    if (mid) VMC(8); else VMC(4);
    BARX();
    // s5: MMA(s4 = q1) + refill av(buf1,kk0,q0) | B(buf1,kk0) | stage A-kk1(ta+2)
    MMA_RDA(1, 1, 0, 0);
    LDB4(bv, 1, 0);
    if (mid) STAGE(0, 0, 1, ta + 2);
    BARX();
    // s6: MMA(s5 = q0) + refill av(buf1,kk0,q1) | stage B-kk1(ta+2) | VMC(8|0)
    MMA_RDA(0, 1, 0, 1);
    if (mid) STAGE(0, 1, 1, ta + 2);
    if (mid) VMC(8); else VMC(0);
    BARX();
    // s7: MMA(s6 = q1) + refill av(buf1,kk1,q0) | B(buf1,kk1) | stage A-kk0(tb+2)
    MMA_RDA(1, 1, 1, 0);
    LDB4(bv, 1, 1);
    if (mid) STAGE(1, 0, 0, tb + 2);
    BARX();
    // s8: MMA(s7 = q0) + refill av(buf1,kk1,q1) | stage B-kk0(tb+2) | VMC(8)
    MMA_RDA(0, 1, 1, 1);
    if (mid) STAGE(1, 1, 0, tb + 2);
    if (mid) VMC(8);
    BARX();
  }
  // trailing: slot ph8's cluster (q1 of last tile)
  MMA16(1);

  if (!FUSED) {
    unsigned short* outB = (unsigned short*)outP;
    #pragma unroll
    for (int mf = 0; mf < 8; mf++)
      #pragma unroll
      for (int nf = 0; nf < 4; nf++) {
        int row = row0 + wr * 128 + mf * 16 + kl * 4;
        int col = col0 + wc * 64 + nf * 16 + l15;
        unsigned short* o = outB + (size_t)row * N + col;
        #pragma unroll
        for (int r = 0; r < 4; r++) o[(size_t)r * N] = f2bf(acc[mf][nf][r]);
      }
  } else {
    #pragma unroll
    for (int nf = 0; nf < 4; nf++) {
      int col = col0 + wc * 64 + nf * 16 + l15;
      float bias = colBias[col];
      float s = 0.f;
      #pragma unroll
      for (int mf = 0; mf < 8; mf++) {
        int rbase = row0 + wr * 128 + mf * 16 + kl * 4;
        #pragma unroll
        for (int r = 0; r < 4; r++)
          s += rowW[rbase + r] * tanhf(acc[mf][nf][r] + bias);
      }
      s += __shfl_xor(s, 16, 64);
      s += __shfl_xor(s, 32, 64);
      if (l < 16) P[(size_t)(rb * 2 + wr) * N + col] = s;
    }
  }
}

// ---------------- final deterministic reduction ----------------
__global__ void k_final(const float* __restrict__ P, const float* __restrict__ emb,
                        const float* __restrict__ wf, const float* __restrict__ wfb,
                        float* __restrict__ out) {
  int e = blockIdx.x * 256 + threadIdx.x;
  float s = 0.f;
  for (int r = 0; r < 32; r++) s += P[(size_t)r * NE + e];
  float c = wfb[0];
  #pragma unroll
  for (int k = 0; k < NEMB; k++) c += emb[e * NEMB + k] * wf[NN + k];
  out[e] = s + c;
}

extern "C" void kernel_launch(void* const* d_in, const int* in_sizes, int n_in,
                              void* d_out, int out_size, void* d_ws, size_t ws_size,
                              hipStream_t stream) {
  const float* x    = (const float*)d_in[0];
  const int*   ei   = (const int*)d_in[1];
  const float* ew   = (const float*)d_in[2];
  const float* gcnw = (const float*)d_in[3];
  const float* gcnb = (const float*)d_in[4];
  const float* wqw  = (const float*)d_in[5];
  const float* wqb  = (const float*)d_in[6];
  const float* emb  = (const float*)d_in[7];
  const float* wfw  = (const float*)d_in[8];
  const float* wfb  = (const float*)d_in[9];
  float* out = (float*)d_out;

  char* ws = (char*)d_ws;
  size_t off = 0;
  auto alloc = [&](size_t b) { char* p = ws + off; off += (b + 255) & ~(size_t)255; return p; };

  unsigned short* wq16  = (unsigned short*)alloc((size_t)NE * NN * 2); // 256MB
  unsigned short* h     = (unsigned short*)alloc((size_t)NN * NN * 2); // 32MB (bf16 now)
  unsigned short* x16   = (unsigned short*)alloc((size_t)NN * NN * 2); // 32MB
  unsigned short* w16   = (unsigned short*)alloc((size_t)NN * NN * 2); // 32MB
  unsigned short* h1b   = (unsigned short*)alloc((size_t)NN * NN * 2); // 32MB
  float* deg    = (float*)alloc(NN * 4);
  float* dis    = (float*)alloc(NN * 4);
  int*   cnt    = (int*)alloc(NN * 4);
  int*   cursor = (int*)alloc(NN * 4);
  int*   starts = (int*)alloc(NN * 4);
  int*   csr_e  = (int*)alloc(NE * 4);
  int*   csr_row= (int*)alloc(NE * 4);
  float* csr_nrm= (float*)alloc(NE * 4);
  float* P      = (float*)alloc((size_t)32 * NE * 4);                  // 4MB

  hipMemsetAsync(cnt, 0, NN * 4 * 2, stream);  // zero cnt + cursor

  k_deg_init<<<NN / 256, 256, 0, stream>>>(deg);
  k_edge_accum<<<NE / 256, 256, 0, stream>>>(ei, ew, deg, cnt);
  k_dis<<<NN / 256, 256, 0, stream>>>(deg, dis);
  k_scan<<<1, 1024, 0, stream>>>(cnt, starts);
  k_fill<<<NE / 256, 256, 0, stream>>>(ei, starts, cursor, csr_e);
  k_sortnorm<<<NN / 256, 256, 0, stream>>>(ei, ew, starts, cnt, dis, csr_e, csr_row, csr_nrm);

  k_f2bf<<<1024, 256, 0, stream>>>(x, x16, (long)NN * NN / 8);
  k_f2bf<<<1024, 256, 0, stream>>>(gcnw, w16, (long)NN * NN / 8);
  k_f2bf<<<2048, 256, 0, stream>>>(wqw, wq16, (long)NE * NN / 8);

  // h = x @ gcn_w.T   (M=N=K=4096): 16x16 blocks of 256x256 (bf16 out)
  gemm8<false><<<16 * 16, 512, 0, stream>>>(x16, w16, NN, NN, 16, h, nullptr, nullptr, nullptr);

  // aggregate + tanh -> H1 (bf16)
  k_agg<<<NN, 256, 0, stream>>>(h, dis, starts, cnt, csr_row, csr_nrm, gcnb, h1b);

  // fused: P[rb*2+wr][e] = sum_rows wf[row] * tanh(H1 @ wq_w.T + wq_b)
  gemm8<true><<<16 * 128, 512, 0, stream>>>(h1b, wq16, NE, NN, 16, nullptr, wqb, wfw, P);

  k_final<<<NE / 256, 256, 0, stream>>>(P, emb, wfw, wfb, out);
}